// Round 1
// baseline (80.206 us; speedup 1.0000x reference)
//
#include <hip/hip_runtime.h>
#include <stdint.h>

typedef __bf16 bf16_t;
typedef __bf16 bf16x8 __attribute__((ext_vector_type(8)));
typedef float f32x4 __attribute__((ext_vector_type(4)));
typedef unsigned short ushort8 __attribute__((ext_vector_type(8)));

#define M_DIM 16384
#define N_DIM 1024
#define K_DIM 1024
#define BM 128
#define BN 128
#define BK 64

// ---------------- x: f32 -> bf16 (RNE), vectorized ----------------
__global__ void cvt_x_bf16(const float* __restrict__ x,
                           unsigned short* __restrict__ xb, int n8) {
    int i = blockIdx.x * blockDim.x + threadIdx.x;
    int stride = gridDim.x * blockDim.x;
    for (; i < n8; i += stride) {
        const float4* p = (const float4*)(x + (size_t)i * 8);
        float4 v0 = p[0], v1 = p[1];
        float vv[8] = {v0.x, v0.y, v0.z, v0.w, v1.x, v1.y, v1.z, v1.w};
        ushort8 o;
#pragma unroll
        for (int j = 0; j < 8; ++j) {
            uint32_t u = __builtin_bit_cast(uint32_t, vv[j]);
            u = u + 0x7FFFu + ((u >> 16) & 1u);   // round-to-nearest-even
            o[j] = (unsigned short)(u >> 16);
        }
        *(ushort8*)(xb + (size_t)i * 8) = o;
    }
}

// ------- W: binarize (exact reference semantics) + transpose to [N][K] -------
__global__ void bin_transpose_w(const float* __restrict__ W,
                                unsigned short* __restrict__ WbT) {
    __shared__ unsigned short t[64][68];   // +4 pad: avoid worst bank conflicts
    int tj = blockIdx.x;                   // n tile
    int ti = blockIdx.y;                   // k tile
    int tid = threadIdx.x;
    int c4 = (tid & 15) * 4;
    int r0 = tid >> 4;                     // 0..15
#pragma unroll
    for (int p = 0; p < 4; ++p) {
        int r = r0 + p * 16;               // k row within tile
        float4 v = *(const float4*)(W + (size_t)(ti * 64 + r) * N_DIM + tj * 64 + c4);
        // reference: +1 iff (w+1)/2 > 0.5 (round-half-even at exactly 0.5 -> 0 -> -1)
        t[r][c4 + 0] = ((v.x + 1.0f) * 0.5f > 0.5f) ? 0x3F80 : 0xBF80;
        t[r][c4 + 1] = ((v.y + 1.0f) * 0.5f > 0.5f) ? 0x3F80 : 0xBF80;
        t[r][c4 + 2] = ((v.z + 1.0f) * 0.5f > 0.5f) ? 0x3F80 : 0xBF80;
        t[r][c4 + 3] = ((v.w + 1.0f) * 0.5f > 0.5f) ? 0x3F80 : 0xBF80;
    }
    __syncthreads();
#pragma unroll
    for (int p = 0; p < 4; ++p) {
        int rn = r0 + p * 16;              // n row within tile
        ushort4 o;
        o.x = t[c4 + 0][rn];
        o.y = t[c4 + 1][rn];
        o.z = t[c4 + 2][rn];
        o.w = t[c4 + 3][rn];
        *(ushort4*)(WbT + (size_t)(tj * 64 + rn) * K_DIM + ti * 64 + c4) = o;
    }
}

// ---------------- bf16 GEMM: C[M][N] = A[M][K] * Bt[N][K]^T + bias ----------------
__device__ __forceinline__ void gload_lds16(const bf16_t* g, bf16_t* l) {
    __builtin_amdgcn_global_load_lds(
        (const __attribute__((address_space(1))) void*)(g),
        (__attribute__((address_space(3))) void*)(l),
        16, 0, 0);
}

__global__ __launch_bounds__(256) void bgemm(const bf16_t* __restrict__ A,
                                             const bf16_t* __restrict__ Bt,
                                             const float* __restrict__ bias,
                                             float* __restrict__ C) {
    __shared__ __align__(16) bf16_t As[BM * BK];
    __shared__ __align__(16) bf16_t Bs[BN * BK];

    const int nwg = (M_DIM / BM) * (N_DIM / BN);   // 1024, %8==0 -> simple swizzle ok
    int bid = blockIdx.x;
    int swz = (bid & 7) * (nwg >> 3) + (bid >> 3); // XCD-aware, bijective
    int tile_m = swz % (M_DIM / BM);
    int tile_n = swz / (M_DIM / BM);               // consecutive swz share B panel
    int bm0 = tile_m * BM;
    int bn0 = tile_n * BN;

    int tid = threadIdx.x;
    int wave = tid >> 6;
    int lane = tid & 63;
    int wr = wave >> 1, wc = wave & 1;

    f32x4 acc[4][4];
#pragma unroll
    for (int m = 0; m < 4; ++m)
#pragma unroll
        for (int n = 0; n < 4; ++n)
            acc[m][n] = (f32x4)(0.0f);

    // staging addressing: wave w stages rows [w*32, w*32+32) of each tile,
    // chunk i covers 8 rows; lane -> (row = l>>3, 16B = 8 bf16 at (l&7)*8)
    int srow = wave * 32 + (lane >> 3);
    int scol = (lane & 7) * 8;
    const bf16_t* gA = A + (size_t)(bm0 + srow) * K_DIM + scol;
    const bf16_t* gB = Bt + (size_t)(bn0 + srow) * K_DIM + scol;
    bf16_t* lA = As + wave * 2048;   // wave*4096 bytes
    bf16_t* lB = Bs + wave * 2048;

    for (int kt = 0; kt < K_DIM; kt += BK) {
#pragma unroll
        for (int i = 0; i < 4; ++i)
            gload_lds16(gA + (size_t)i * 8 * K_DIM + kt, lA + i * 512);
#pragma unroll
        for (int i = 0; i < 4; ++i)
            gload_lds16(gB + (size_t)i * 8 * K_DIM + kt, lB + i * 512);
        __syncthreads();   // compiler drains vmcnt before s_barrier

#pragma unroll
        for (int kk = 0; kk < BK; kk += 32) {
            bf16x8 af[4], bf[4];
            int ka = kk + (lane >> 4) * 8;
#pragma unroll
            for (int m = 0; m < 4; ++m) {
                int row = wr * 64 + m * 16 + (lane & 15);
                af[m] = *(const bf16x8*)(As + row * BK + ka);
            }
#pragma unroll
            for (int n = 0; n < 4; ++n) {
                int row = wc * 64 + n * 16 + (lane & 15);
                bf[n] = *(const bf16x8*)(Bs + row * BK + ka);
            }
#pragma unroll
            for (int m = 0; m < 4; ++m)
#pragma unroll
                for (int n = 0; n < 4; ++n)
                    acc[m][n] = __builtin_amdgcn_mfma_f32_16x16x32_bf16(
                        af[m], bf[n], acc[m][n], 0, 0, 0);
        }
        __syncthreads();
    }

    // epilogue: C/D layout col = lane&15, row = (lane>>4)*4 + reg
#pragma unroll
    for (int n = 0; n < 4; ++n) {
        int col = bn0 + wc * 64 + n * 16 + (lane & 15);
        float bv = bias[col];
#pragma unroll
        for (int m = 0; m < 4; ++m) {
            int row0 = bm0 + wr * 64 + m * 16 + ((lane >> 4) << 2);
#pragma unroll
            for (int j = 0; j < 4; ++j)
                C[(size_t)(row0 + j) * N_DIM + col] = acc[m][n][j] + bv;
        }
    }
}

// ---------------- fallback (only if workspace too small) ----------------
__global__ void naive_bin_dense(const float* __restrict__ x,
                                const float* __restrict__ W,
                                const float* __restrict__ b,
                                float* __restrict__ out) {
    int col = blockIdx.x * 256 + threadIdx.x;
    int row = blockIdx.y;
    float acc = 0.0f;
    for (int k = 0; k < K_DIM; ++k) {
        float s = ((W[(size_t)k * N_DIM + col] + 1.0f) * 0.5f > 0.5f) ? 1.0f : -1.0f;
        acc += x[(size_t)row * K_DIM + k] * s;
    }
    out[(size_t)row * N_DIM + col] = acc + b[col];
}

extern "C" void kernel_launch(void* const* d_in, const int* in_sizes, int n_in,
                              void* d_out, int out_size, void* d_ws, size_t ws_size,
                              hipStream_t stream) {
    const float* x = (const float*)d_in[0];
    const float* W = (const float*)d_in[1];
    const float* b = (const float*)d_in[2];
    float* out = (float*)d_out;

    size_t xb_bytes = (size_t)M_DIM * K_DIM * sizeof(unsigned short);
    size_t wb_bytes = (size_t)K_DIM * N_DIM * sizeof(unsigned short);

    if (ws_size >= xb_bytes + wb_bytes) {
        unsigned short* xb = (unsigned short*)d_ws;
        unsigned short* wbt = (unsigned short*)((char*)d_ws + xb_bytes);
        hipLaunchKernelGGL(cvt_x_bf16, dim3(2048), dim3(256), 0, stream,
                           x, xb, (M_DIM * K_DIM) / 8);
        hipLaunchKernelGGL(bin_transpose_w, dim3(N_DIM / 64, K_DIM / 64), dim3(256),
                           0, stream, W, wbt);
        hipLaunchKernelGGL(bgemm, dim3((M_DIM / BM) * (N_DIM / BN)), dim3(256), 0, stream,
                           (const bf16_t*)xb, (const bf16_t*)wbt, b, out);
    } else {
        hipLaunchKernelGGL(naive_bin_dense, dim3(N_DIM / 256, M_DIM), dim3(256),
                           0, stream, x, W, b, out);
    }
}

// Round 2
// 64.668 us; speedup vs baseline: 1.2403x; 1.2403x over previous
//
#include <hip/hip_runtime.h>
#include <stdint.h>

typedef __bf16 bf16_t;
typedef __bf16 bf16x8 __attribute__((ext_vector_type(8)));
typedef float f32x4 __attribute__((ext_vector_type(4)));
typedef unsigned short ushort8 __attribute__((ext_vector_type(8)));

#define M_DIM 16384
#define N_DIM 1024
#define K_DIM 1024
#define BM 128
#define BN 256
#define BK 64
#define NT (K_DIM / BK)                 // 16 K-tiles
#define A_ELEMS (BM * BK)               // 8192 elems (16 KB)
#define TILE_ELEMS ((BM + BN) * BK)     // 24576 elems (48 KB per buffer)

// ---------------- x: f32 -> bf16 (RNE), vectorized ----------------
__global__ void cvt_x_bf16(const float* __restrict__ x,
                           unsigned short* __restrict__ xb, int n8) {
    int i = blockIdx.x * blockDim.x + threadIdx.x;
    int stride = gridDim.x * blockDim.x;
    for (; i < n8; i += stride) {
        const float4* p = (const float4*)(x + (size_t)i * 8);
        float4 v0 = p[0], v1 = p[1];
        float vv[8] = {v0.x, v0.y, v0.z, v0.w, v1.x, v1.y, v1.z, v1.w};
        ushort8 o;
#pragma unroll
        for (int j = 0; j < 8; ++j) {
            uint32_t u = __builtin_bit_cast(uint32_t, vv[j]);
            u = u + 0x7FFFu + ((u >> 16) & 1u);   // round-to-nearest-even
            o[j] = (unsigned short)(u >> 16);
        }
        *(ushort8*)(xb + (size_t)i * 8) = o;
    }
}

// ------- W: binarize (exact reference semantics) + transpose to [N][K] -------
__global__ void bin_transpose_w(const float* __restrict__ W,
                                unsigned short* __restrict__ WbT) {
    __shared__ unsigned short t[64][68];
    int tj = blockIdx.x;                   // n tile
    int ti = blockIdx.y;                   // k tile
    int tid = threadIdx.x;
    int c4 = (tid & 15) * 4;
    int r0 = tid >> 4;
#pragma unroll
    for (int p = 0; p < 4; ++p) {
        int r = r0 + p * 16;
        float4 v = *(const float4*)(W + (size_t)(ti * 64 + r) * N_DIM + tj * 64 + c4);
        // reference: +1 iff (w+1)/2 > 0.5 (round-half-even at exactly 0.5 -> -1)
        t[r][c4 + 0] = ((v.x + 1.0f) * 0.5f > 0.5f) ? 0x3F80 : 0xBF80;
        t[r][c4 + 1] = ((v.y + 1.0f) * 0.5f > 0.5f) ? 0x3F80 : 0xBF80;
        t[r][c4 + 2] = ((v.z + 1.0f) * 0.5f > 0.5f) ? 0x3F80 : 0xBF80;
        t[r][c4 + 3] = ((v.w + 1.0f) * 0.5f > 0.5f) ? 0x3F80 : 0xBF80;
    }
    __syncthreads();
#pragma unroll
    for (int p = 0; p < 4; ++p) {
        int rn = r0 + p * 16;
        ushort4 o;
        o.x = t[c4 + 0][rn];
        o.y = t[c4 + 1][rn];
        o.z = t[c4 + 2][rn];
        o.w = t[c4 + 3][rn];
        *(ushort4*)(WbT + (size_t)(tj * 64 + rn) * K_DIM + ti * 64 + c4) = o;
    }
}

// ---------------- pipelined bf16 GEMM: C = A * Bt^T + bias ----------------
__device__ __forceinline__ void gload16(const bf16_t* g, const bf16_t* l) {
    __builtin_amdgcn_global_load_lds(
        (const __attribute__((address_space(1))) void*)(g),
        (__attribute__((address_space(3))) void*)(l),
        16, 0, 0);
}

__global__ __launch_bounds__(512, 2) void bgemm(const bf16_t* __restrict__ A,
                                                const bf16_t* __restrict__ Bt,
                                                const float* __restrict__ bias,
                                                float* __restrict__ C) {
    // 3 LDS buffers -> stage tile t+2 while computing tile t (provably race-free:
    // target buffer's last reader was tile t-1, retired at a prior barrier).
    __shared__ __align__(16) bf16_t lds[3 * TILE_ELEMS];   // 144 KB

    const int nwg = (M_DIM / BM) * (N_DIM / BN);   // 512, %8==0
    int bid = blockIdx.x;
    int swz = (bid & 7) * (nwg >> 3) + (bid >> 3); // XCD-aware, bijective
    int tile_m = swz % (M_DIM / BM);
    int tile_n = swz / (M_DIM / BM);
    int bm0 = tile_m * BM;
    int bn0 = tile_n * BN;

    int tid = threadIdx.x;
    int w = tid >> 6;                  // 8 waves: 2 (M) x 4 (N)
    int l = tid & 63;
    int wr = w >> 2, wc = w & 3;       // per-wave 64x64 output
    int lr = l & 15, lk = l >> 4, l7 = l & 7;
    int cgg = (l & 7) ^ (l >> 3);      // inverse-swizzled source col-group (T2)

    // stage helpers: LDS dest is wave-uniform base + lane*16 (linear);
    // swizzle realized by permuting the per-lane GLOBAL source (rule #21).
    auto stageA = [&](int t, int boff) {
#pragma unroll
        for (int k = 0; k < 2; ++k) {
            int row = k * 64 + w * 8 + (l >> 3);
            gload16(A + (size_t)(bm0 + row) * K_DIM + t * BK + cgg * 8,
                    lds + boff + k * 4096 + w * 512);
        }
    };
    auto stageB1 = [&](int t, int boff, int k) {
        int row = k * 64 + w * 8 + (l >> 3);
        gload16(Bt + (size_t)(bn0 + row) * K_DIM + t * BK + cgg * 8,
                lds + boff + A_ELEMS + k * 4096 + w * 512);
    };

    f32x4 acc[4][4];
#pragma unroll
    for (int m = 0; m < 4; ++m)
#pragma unroll
        for (int n = 0; n < 4; ++n)
            acc[m][n] = (f32x4)(0.0f);

    // ---- prologue: stage tiles 0 and 1; wait for tile 0 only (6 in flight) ----
    stageA(0, 0);
#pragma unroll
    for (int k = 0; k < 4; ++k) stageB1(0, 0, k);
    stageA(1, TILE_ELEMS);
#pragma unroll
    for (int k = 0; k < 4; ++k) stageB1(1, TILE_ELEMS, k);
    asm volatile("s_waitcnt vmcnt(6)" ::: "memory");
    __builtin_amdgcn_s_barrier();

    int cboff = 0;                     // compute buffer offset
    int sboff = 2 * TILE_ELEMS;        // stage buffer offset (tile t+2)

    for (int t = 0; t < NT; ++t) {
        const bf16_t* Ab = lds + cboff;
        const bf16_t* Bb = lds + cboff + A_ELEMS;

        // ---- phase 1: read af (all) + bf[0..1]; stage A + B0 of tile t+2 ----
        bf16x8 af[4][2];
#pragma unroll
        for (int m = 0; m < 4; ++m)
#pragma unroll
            for (int kk = 0; kk < 2; ++kk)
                af[m][kk] = *(const bf16x8*)(Ab + (wr * 64 + m * 16 + lr) * BK
                                             + (((kk * 4 + lk) ^ l7) * 8));
        bf16x8 bf0[2][2];
#pragma unroll
        for (int n = 0; n < 2; ++n)
#pragma unroll
            for (int kk = 0; kk < 2; ++kk)
                bf0[n][kk] = *(const bf16x8*)(Bb + (wc * 64 + n * 16 + lr) * BK
                                              + (((kk * 4 + lk) ^ l7) * 8));
        if (t + 2 < NT) {
            stageA(t + 2, sboff);
            stageB1(t + 2, sboff, 0);
        }
        __builtin_amdgcn_s_barrier();
        __builtin_amdgcn_s_setprio(1);
#pragma unroll
        for (int m = 0; m < 4; ++m)
#pragma unroll
            for (int n = 0; n < 2; ++n)
#pragma unroll
                for (int kk = 0; kk < 2; ++kk)
                    acc[m][n] = __builtin_amdgcn_mfma_f32_16x16x32_bf16(
                        af[m][kk], bf0[n][kk], acc[m][n], 0, 0, 0);
        __builtin_amdgcn_s_setprio(0);
        __builtin_amdgcn_s_barrier();

        // ---- phase 2: read bf[2..3]; stage B1..B3 of tile t+2 ----
        bf16x8 bf1[2][2];
#pragma unroll
        for (int n = 0; n < 2; ++n)
#pragma unroll
            for (int kk = 0; kk < 2; ++kk)
                bf1[n][kk] = *(const bf16x8*)(Bb + (wc * 64 + (n + 2) * 16 + lr) * BK
                                              + (((kk * 4 + lk) ^ l7) * 8));
        if (t + 2 < NT) {
#pragma unroll
            for (int k = 1; k < 4; ++k) stageB1(t + 2, sboff, k);
        }
        __builtin_amdgcn_s_barrier();
        __builtin_amdgcn_s_setprio(1);
#pragma unroll
        for (int m = 0; m < 4; ++m)
#pragma unroll
            for (int n = 0; n < 2; ++n)
#pragma unroll
                for (int kk = 0; kk < 2; ++kk)
                    acc[m][n + 2] = __builtin_amdgcn_mfma_f32_16x16x32_bf16(
                        af[m][kk], bf1[n][kk], acc[m][n + 2], 0, 0, 0);
        __builtin_amdgcn_s_setprio(0);

        // ---- tile boundary: tile t+1 must be resident; keep t+2 in flight ----
        if (t < NT - 1) {
            if (t + 2 < NT)
                asm volatile("s_waitcnt vmcnt(6)" ::: "memory");
            else
                asm volatile("s_waitcnt vmcnt(0)" ::: "memory");
            __builtin_amdgcn_s_barrier();
        }

        cboff += TILE_ELEMS; if (cboff == 3 * TILE_ELEMS) cboff = 0;
        sboff += TILE_ELEMS; if (sboff == 3 * TILE_ELEMS) sboff = 0;
    }

    // ---- epilogue: C/D layout col = lane&15, row = (lane>>4)*4 + reg ----
#pragma unroll
    for (int n = 0; n < 4; ++n) {
        int col = bn0 + wc * 64 + n * 16 + lr;
        float bv = bias[col];
#pragma unroll
        for (int m = 0; m < 4; ++m) {
            int row0 = bm0 + wr * 64 + m * 16 + lk * 4;
#pragma unroll
            for (int j = 0; j < 4; ++j)
                C[(size_t)(row0 + j) * N_DIM + col] = acc[m][n][j] + bv;
        }
    }
}

// ---------------- fallback (only if workspace too small) ----------------
__global__ void naive_bin_dense(const float* __restrict__ x,
                                const float* __restrict__ W,
                                const float* __restrict__ b,
                                float* __restrict__ out) {
    int col = blockIdx.x * 256 + threadIdx.x;
    int row = blockIdx.y;
    float acc = 0.0f;
    for (int k = 0; k < K_DIM; ++k) {
        float s = ((W[(size_t)k * N_DIM + col] + 1.0f) * 0.5f > 0.5f) ? 1.0f : -1.0f;
        acc += x[(size_t)row * K_DIM + k] * s;
    }
    out[(size_t)row * N_DIM + col] = acc + b[col];
}

extern "C" void kernel_launch(void* const* d_in, const int* in_sizes, int n_in,
                              void* d_out, int out_size, void* d_ws, size_t ws_size,
                              hipStream_t stream) {
    const float* x = (const float*)d_in[0];
    const float* W = (const float*)d_in[1];
    const float* b = (const float*)d_in[2];
    float* out = (float*)d_out;

    size_t xb_bytes = (size_t)M_DIM * K_DIM * sizeof(unsigned short);
    size_t wb_bytes = (size_t)K_DIM * N_DIM * sizeof(unsigned short);

    if (ws_size >= xb_bytes + wb_bytes) {
        unsigned short* xb = (unsigned short*)d_ws;
        unsigned short* wbt = (unsigned short*)((char*)d_ws + xb_bytes);
        hipLaunchKernelGGL(cvt_x_bf16, dim3(2048), dim3(256), 0, stream,
                           x, xb, (M_DIM * K_DIM) / 8);
        hipLaunchKernelGGL(bin_transpose_w, dim3(N_DIM / 64, K_DIM / 64), dim3(256),
                           0, stream, W, wbt);
        hipLaunchKernelGGL(bgemm, dim3((M_DIM / BM) * (N_DIM / BN)), dim3(512), 0, stream,
                           (const bf16_t*)xb, (const bf16_t*)wbt, b, out);
    } else {
        hipLaunchKernelGGL(naive_bin_dense, dim3(N_DIM / 256, M_DIM), dim3(256),
                           0, stream, x, W, b, out);
    }
}